// Round 2
// baseline (3414.402 us; speedup 1.0000x reference)
//
#include <hip/hip_runtime.h>
#include <math.h>

#define IN_DIM 1024
#define E_DIM  256
#define N_EXP  512
#define N_TOK  131072   // 64 * 2048
#define TM     32       // tokens per block
#define BK     32       // k-chunk for GEMM1
#define XS_STR 36       // floats per x-tile LDS row (16B-aligned, 2-way-free reads)
#define WS_STR 36       // floats per W-tile LDS row

typedef double d4 __attribute__((ext_vector_type(4)));

__device__ __forceinline__ void ins2(double v, int c,
                                     double& v1, int& i1, double& v2, int& i2)
{
    if (v > v1 || (v == v1 && c < i1)) { v2 = v1; i2 = i1; v1 = v; i1 = c; }
    else if (v > v2 || (v == v2 && c < i2)) { v2 = v; i2 = c; }
}

// ---------------------------------------------------------------------------
// Kernel A: L2-normalize center rows in fp64, write TRANSPOSED: cTd[k][ctr]
// ---------------------------------------------------------------------------
__global__ __launch_bounds__(64) void center_norm_kernel(
    const float* __restrict__ centers, double* __restrict__ cTd)
{
    const int ctr  = blockIdx.x;   // 0..511
    const int lane = threadIdx.x;  // 0..63
    const float* row = centers + (size_t)ctr * E_DIM;
    double v[4];
    double s = 0.0;
#pragma unroll
    for (int i = 0; i < 4; ++i) { v[i] = (double)row[lane + 64 * i]; s = fma(v[i], v[i], s); }
#pragma unroll
    for (int off = 32; off >= 1; off >>= 1) s += __shfl_xor(s, off, 64);
    const double inv = 1.0 / fmax(sqrt(s), 1e-12);
#pragma unroll
    for (int i = 0; i < 4; ++i)
        cTd[(size_t)(lane + 64 * i) * N_EXP + ctr] = v[i] * inv;
}

// ---------------------------------------------------------------------------
// Kernel B: fused fp64-accurate router on the f64 matrix pipe.
// 256 threads = 4 waves. Wave wv owns expert cols [64*wv, 64*wv+64) in GEMM1
// and center cols [128*wv, 128*wv+128) in GEMM2 (4 passes of 32).
// mfma_f64_16x16x4 layouts: A[row=l&15][k=l>>4], B[k=l>>4][col=l&15],
// D[row=(l>>4)*4+i][col=l&15].
// GEMM1 is software-pipelined: next K-tile is prefetched into registers
// during the current tile's MFMA phase (hides HBM/L2 latency; T14 pattern).
// ---------------------------------------------------------------------------
__global__ __launch_bounds__(256, 2) void router_kernel(
    const float* __restrict__ x, const float* __restrict__ W,
    const float* __restrict__ bias, const double* __restrict__ cTd,
    float* __restrict__ out)
{
    __shared__ __align__(16) char smem_raw[65536];   // 64 KB union of all phases
    const int tid  = threadIdx.x;
    const int lane = tid & 63;
    const int wv   = tid >> 6;     // wave 0..3
    const int r    = lane & 15;    // frag row/col
    const int q    = lane >> 4;    // frag k-slot / row-group
    const int tokBase = blockIdx.x * TM;

    float* xs  = (float*)smem_raw;                        // [32][XS_STR] f32
    float* wsm = (float*)(smem_raw + TM * XS_STR * 4);    // [256][WS_STR] f32

    d4 acc[2][4];                                         // [m-frag][n-frag]
#pragma unroll
    for (int m = 0; m < 2; ++m)
#pragma unroll
        for (int n = 0; n < 4; ++n) acc[m][n] = (d4){0.0, 0.0, 0.0, 0.0};

    const int lt = tid >> 3;           // staging row 0..31
    const int lk = (tid & 7) * 4;      // staging k 0,4,...,28

    const float* xp = x + (size_t)(tokBase + lt) * IN_DIM + lk;
    const float* wp = W + (size_t)lt * IN_DIM + lk;

    // ---------------- GEMM1 (f64 MFMA, reg-prefetch pipelined) --------------
    // prologue: preload tile 0 into registers
    float4 xv = *(const float4*)xp;
    float4 wreg[8];
#pragma unroll
    for (int p = 0; p < 8; ++p)
        wreg[p] = *(const float4*)(wp + (size_t)(p * 32) * IN_DIM);

    for (int k0 = 0; k0 < IN_DIM; k0 += BK) {
        __syncthreads();   // previous MFMA phase done reading LDS (no-op on iter 0)
        *(float4*)(xs + lt * XS_STR + lk) = xv;
#pragma unroll
        for (int p = 0; p < 8; ++p)
            *(float4*)(wsm + (lt + p * 32) * WS_STR + lk) = wreg[p];
        __syncthreads();   // tile visible to all waves

        if (k0 + BK < IN_DIM) {   // issue next-tile loads; land during MFMA phase
            xv = *(const float4*)(xp + k0 + BK);
#pragma unroll
            for (int p = 0; p < 8; ++p)
                wreg[p] = *(const float4*)(wp + (size_t)(p * 32) * IN_DIM + k0 + BK);
        }

#pragma unroll
        for (int kk = 0; kk < 8; ++kk) {
            const int k = kk * 4 + q;
            const double a0 = (double)xs[r * XS_STR + k];          // rows 0..15
            const double a1 = (double)xs[(16 + r) * XS_STR + k];   // rows 16..31
#pragma unroll
            for (int n = 0; n < 4; ++n) {
                const double b = (double)wsm[(wv * 64 + n * 16 + r) * WS_STR + k];
                acc[0][n] = __builtin_amdgcn_mfma_f64_16x16x4f64(a0, b, acc[0][n], 0, 0, 0);
                acc[1][n] = __builtin_amdgcn_mfma_f64_16x16x4f64(a1, b, acc[1][n], 0, 0, 0);
            }
        }
    }
    __syncthreads();   // all waves done with xs/wsm before LDS is repurposed

    // ---------------- bias (fp64) --------------------------------------------
#pragma unroll
    for (int n = 0; n < 4; ++n) {
        const double bb = (double)bias[wv * 64 + n * 16 + r];
#pragma unroll
        for (int m = 0; m < 2; ++m)
#pragma unroll
            for (int i = 0; i < 4; ++i) acc[m][n][i] += bb;
    }

    // ---------------- per-token L2 norm (cross-wave via 1KB LDS) -------------
    double* partials = (double*)smem_raw;      // [4 waves][32 tok]
    double ss[2][4];
#pragma unroll
    for (int m = 0; m < 2; ++m)
#pragma unroll
        for (int i = 0; i < 4; ++i) {
            double s = 0.0;
#pragma unroll
            for (int n = 0; n < 4; ++n) s = fma(acc[m][n][i], acc[m][n][i], s);
            // sum across the 16 col-lanes sharing this token row
#pragma unroll
            for (int off = 8; off >= 1; off >>= 1) s += __shfl_xor(s, off, 64);
            ss[m][i] = s;
        }
    if (r == 0) {
#pragma unroll
        for (int m = 0; m < 2; ++m)
#pragma unroll
            for (int i = 0; i < 4; ++i)
                partials[wv * 32 + m * 16 + q * 4 + i] = ss[m][i];
    }
    __syncthreads();

    double inv[2][4];
#pragma unroll
    for (int m = 0; m < 2; ++m)
#pragma unroll
        for (int i = 0; i < 4; ++i) {
            const int t = m * 16 + q * 4 + i;
            const double s = partials[t] + partials[32 + t] + partials[64 + t] + partials[96 + t];
            inv[m][i] = 1.0 / fmax(sqrt(s), 1e-12);
        }
    __syncthreads();   // all partials reads done before projn overwrites region

    // write NORMALIZED projn[e][tok] (fp64, exactly 64KB)
    double* projn = (double*)smem_raw;   // [256][32]
#pragma unroll
    for (int m = 0; m < 2; ++m)
#pragma unroll
        for (int n = 0; n < 4; ++n)
#pragma unroll
            for (int i = 0; i < 4; ++i)
                projn[(wv * 64 + n * 16 + r) * 32 + m * 16 + q * 4 + i] = acc[m][n][i] * inv[m][i];
    __syncthreads();

    // ---------------- GEMM2 (f64 MFMA) + fused per-lane top-2 ----------------
    // 4 passes x 32 cols per wave: acc2 pressure halved vs 2x64 (spill guard).
    double tv1[2][4], tv2[2][4];
    int    ti1[2][4], ti2[2][4];
#pragma unroll
    for (int m = 0; m < 2; ++m)
#pragma unroll
        for (int i = 0; i < 4; ++i) {
            tv1[m][i] = -1e300; tv2[m][i] = -1e300; ti1[m][i] = 0; ti2[m][i] = 0;
        }

    for (int pass = 0; pass < 4; ++pass) {
        const int colbase = wv * 128 + pass * 32;
        d4 acc2[2][2];
#pragma unroll
        for (int m = 0; m < 2; ++m)
#pragma unroll
            for (int n = 0; n < 2; ++n) acc2[m][n] = (d4){0.0, 0.0, 0.0, 0.0};

        // lane-resolved pointers, strength-reduced k stepping (k = kk*4 + q)
        const double* cb = cTd + (size_t)q * N_EXP + colbase + r;   // B from L2
        const double* pa = projn + q * 32 + r;                      // A from LDS
#pragma unroll 8
        for (int kk = 0; kk < 64; ++kk) {
            const double a0 = pa[0];
            const double a1 = pa[16];
            const double b0 = cb[0];
            const double b1 = cb[16];
            acc2[0][0] = __builtin_amdgcn_mfma_f64_16x16x4f64(a0, b0, acc2[0][0], 0, 0, 0);
            acc2[1][0] = __builtin_amdgcn_mfma_f64_16x16x4f64(a1, b0, acc2[1][0], 0, 0, 0);
            acc2[0][1] = __builtin_amdgcn_mfma_f64_16x16x4f64(a0, b1, acc2[0][1], 0, 0, 0);
            acc2[1][1] = __builtin_amdgcn_mfma_f64_16x16x4f64(a1, b1, acc2[1][1], 0, 0, 0);
            pa += 4 * 32;          // 4 k-rows of projn
            cb += (size_t)4 * N_EXP;
        }
#pragma unroll
        for (int m = 0; m < 2; ++m)
#pragma unroll
            for (int i = 0; i < 4; ++i)
#pragma unroll
                for (int n = 0; n < 2; ++n)
                    ins2(acc2[m][n][i], colbase + n * 16 + r,
                         tv1[m][i], ti1[m][i], tv2[m][i], ti2[m][i]);
    }

    // merge top-2 across the 16 col-lanes of each token row
#pragma unroll
    for (int m = 0; m < 2; ++m)
#pragma unroll
        for (int i = 0; i < 4; ++i) {
#pragma unroll
            for (int off = 8; off >= 1; off >>= 1) {
                const double ov1 = __shfl_xor(tv1[m][i], off, 64);
                const int    oi1 = __shfl_xor(ti1[m][i], off, 64);
                const double ov2 = __shfl_xor(tv2[m][i], off, 64);
                const int    oi2 = __shfl_xor(ti2[m][i], off, 64);
                ins2(ov1, oi1, tv1[m][i], ti1[m][i], tv2[m][i], ti2[m][i]);
                ins2(ov2, oi2, tv1[m][i], ti1[m][i], tv2[m][i], ti2[m][i]);
            }
        }

    __syncthreads();                      // projn dead; reuse LDS for candidates
    double* cand = (double*)smem_raw;     // [4 waves][32 tok][4]
    if (r == 0) {
#pragma unroll
        for (int m = 0; m < 2; ++m)
#pragma unroll
            for (int i = 0; i < 4; ++i) {
                const int t = m * 16 + q * 4 + i;
                double* cd = cand + ((wv * 32 + t) << 2);
                cd[0] = tv1[m][i]; cd[1] = (double)ti1[m][i];
                cd[2] = tv2[m][i]; cd[3] = (double)ti2[m][i];
            }
    }
    __syncthreads();

    if (tid < 32) {
        double v1 = -1e300, v2 = -1e300;
        int    i1 = 0, i2 = 0;
        for (int s = 0; s < 4; ++s) {
            const double* cd = cand + ((s * 32 + tid) << 2);
            ins2(cd[0], (int)cd[1], v1, i1, v2, i2);
            ins2(cd[2], (int)cd[3], v1, i1, v2, i2);
        }
        const double e  = exp(v2 - v1);    // <= 1
        const double dn = 1.0 + e;
        const size_t g  = (size_t)tokBase + tid;
        out[g * 2 + 0] = (float)(1.0 / dn);
        out[g * 2 + 1] = (float)(e / dn);
        out[(size_t)2 * N_TOK + g * 2 + 0] = (float)i1;
        out[(size_t)2 * N_TOK + g * 2 + 1] = (float)i2;
    }
}

// ---------------------------------------------------------------------------
extern "C" void kernel_launch(void* const* d_in, const int* in_sizes, int n_in,
                              void* d_out, int out_size, void* d_ws, size_t ws_size,
                              hipStream_t stream)
{
    const float* x       = (const float*)d_in[0];
    const float* W       = (const float*)d_in[1];
    const float* bias    = (const float*)d_in[2];
    const float* centers = (const float*)d_in[3];
    // d_in[4] = top_k (always 2, hard-coded)
    double* cTd = (double*)d_ws;   // 256 x 512 doubles = 1 MB scratch
    float*  out = (float*)d_out;

    center_norm_kernel<<<N_EXP, 64, 0, stream>>>(centers, cTd);
    router_kernel<<<N_TOK / TM, 256, 0, stream>>>(x, W, bias, cTd, out);
}

// Round 4
// 2717.617 us; speedup vs baseline: 1.2564x; 1.2564x over previous
//
#include <hip/hip_runtime.h>
#include <math.h>

#define IN_DIM 1024
#define E_DIM  256
#define N_EXP  512
#define N_TOK  131072   // 64 * 2048
#define TM     32       // tokens per block
#define BK     16       // k-chunk for GEMM1 (double-buffered)
#define NT     64       // IN_DIM / BK
#define BUF_BYTES 18432 // (512 + 4096) floats * 4

typedef double d4 __attribute__((ext_vector_type(4)));

__device__ __forceinline__ void ins2(double v, int c,
                                     double& v1, int& i1, double& v2, int& i2)
{
    if (v > v1 || (v == v1 && c < i1)) { v2 = v1; i2 = i1; v1 = v; i1 = c; }
    else if (v > v2 || (v == v2 && c < i2)) { v2 = v; i2 = c; }
}

// async global->LDS, 16B per lane, zero VGPR data movement
__device__ __forceinline__ void gload_lds16(const float* g, float* l)
{
    __builtin_amdgcn_global_load_lds(
        (const __attribute__((address_space(1))) unsigned int*)(g),
        (__attribute__((address_space(3))) unsigned int*)(l),
        16, 0, 0);
}

// ---------------------------------------------------------------------------
// Kernel A: L2-normalize center rows in fp64, write TRANSPOSED: cTd[k][ctr]
// ---------------------------------------------------------------------------
__global__ __launch_bounds__(64) void center_norm_kernel(
    const float* __restrict__ centers, double* __restrict__ cTd)
{
    const int ctr  = blockIdx.x;   // 0..511
    const int lane = threadIdx.x;  // 0..63
    const float* row = centers + (size_t)ctr * E_DIM;
    double v[4];
    double s = 0.0;
#pragma unroll
    for (int i = 0; i < 4; ++i) { v[i] = (double)row[lane + 64 * i]; s = fma(v[i], v[i], s); }
#pragma unroll
    for (int off = 32; off >= 1; off >>= 1) s += __shfl_xor(s, off, 64);
    const double inv = 1.0 / fmax(sqrt(s), 1e-12);
#pragma unroll
    for (int i = 0; i < 4; ++i)
        cTd[(size_t)(lane + 64 * i) * N_EXP + ctr] = v[i] * inv;
}

// ---------------------------------------------------------------------------
// Kernel B: fused fp64-accurate router on the f64 matrix pipe.
// 256 threads = 4 waves. Wave wv owns expert cols [64*wv, 64*wv+64) in GEMM1
// and center cols [128*wv, 128*wv+128) in GEMM2 (2 passes of 64).
// mfma_f64_16x16x4 layouts: A[row=l&15][k=l>>4], B[k=l>>4][col=l&15],
// D[row=(l>>4)*4+i][col=l&15].
//
// GEMM1 staging: global_load_lds (async DMA, no VGPR round-trip) into a
// 2-deep LDS double buffer (BK=16: 18KB/buf). LDS dest is linear
// (base+lane*16); bank conflicts on the fragment reads are fixed by
// pre-swizzling the GLOBAL source f4-column with (row>>1)&3 and applying the
// same XOR on the read side (rule #21: both-sides-or-neither).
// K accumulation order is unchanged vs BK=32 (same ascending 4-k MFMA groups)
// so results stay bit-identical.
// NOTE: no local arrays of LDS pointers (hipcc addrspacecast static-init bug);
// buffer bases are computed as smem_raw + buf*BUF_BYTES at point of use.
// ---------------------------------------------------------------------------
__global__ __launch_bounds__(256, 2) void router_kernel(
    const float* __restrict__ x, const float* __restrict__ W,
    const float* __restrict__ bias, const double* __restrict__ cTd,
    float* __restrict__ out)
{
    __shared__ __align__(16) char smem_raw[65536];   // 64 KB union of all phases
    const int tid  = threadIdx.x;
    const int lane = tid & 63;
    const int wv   = tid >> 6;     // wave 0..3
    const int r    = lane & 15;    // frag row/col
    const int q    = lane >> 4;    // frag k-slot / row-group
    const int tokBase = blockIdx.x * TM;

    // --- staging geometry (per-lane, constant) -----------------------------
    // f4 slot s = p*256 + wv*64 + lane  ->  row = s>>2, physical f4 col = s&3.
    // Stored value must be global f4 col c = (s&3) ^ ((row>>1)&3)
    //   = (lane&3) ^ ((lane>>3)&3)  (independent of p, wv since both shift
    //   row by multiples of 8).
    const int srow = lane >> 2;                        // 0..15
    const int scol = (lane & 3) ^ ((lane >> 3) & 3);   // pre-swizzled f4 col
    const float* xg = x + (size_t)(tokBase + (wv & 1) * 16 + srow) * IN_DIM + scol * 4; // wv<2 only
    const float* wg = W + (size_t)(wv * 16 + srow) * IN_DIM + scol * 4;

    d4 acc[2][4];                                         // [m-frag][n-frag]
#pragma unroll
    for (int m = 0; m < 2; ++m)
#pragma unroll
        for (int n = 0; n < 4; ++n) acc[m][n] = (d4){0.0, 0.0, 0.0, 0.0};

    // read-side swizzle: logical (row, f4col kk) lives at f4col kk^((row>>1)&3);
    // all rows touched by this lane share (row>>1)&3 == (r>>1)&3.
    const int swz   = (r >> 1) & 3;
    const int abase = r * 16 + q;                 // x float offset (row r)
    const int bbase = (wv * 64 + r) * 16 + q;     // W float offset (row wv*64+r)

    // ---------------- GEMM1 (f64 MFMA, async double-buffered) --------------
    {   // prologue: stage tile 0 into buffer 0
        float* b = (float*)smem_raw;
        if (wv < 2) gload_lds16(xg, b + wv * 256);
#pragma unroll
        for (int p = 0; p < 4; ++p)
            gload_lds16(wg + (size_t)p * 64 * IN_DIM, b + 512 + p * 1024 + wv * 256);
    }
    __syncthreads();   // implicit vmcnt(0) drain: tile 0 resident

    int cur = 0;
    for (int t = 0; t < NT; ++t) {
        if (t + 1 < NT) {   // issue next-tile DMA; lands during MFMA phase
            float* b = (float*)(smem_raw + (cur ^ 1) * BUF_BYTES);
            const int k0 = (t + 1) * BK;
            if (wv < 2) gload_lds16(xg + k0, b + wv * 256);
#pragma unroll
            for (int p = 0; p < 4; ++p)
                gload_lds16(wg + (size_t)p * 64 * IN_DIM + k0, b + 512 + p * 1024 + wv * 256);
        }
        const float* xb = (const float*)(smem_raw + cur * BUF_BYTES);
        const float* wb = xb + 512;
#pragma unroll
        for (int kk = 0; kk < 4; ++kk) {
            const int so = 4 * (kk ^ swz);
            const double a0 = (double)xb[abase + so];          // rows 0..15
            const double a1 = (double)xb[abase + 256 + so];    // rows 16..31
#pragma unroll
            for (int n = 0; n < 4; ++n) {
                const double b = (double)wb[bbase + n * 256 + so];
                acc[0][n] = __builtin_amdgcn_mfma_f64_16x16x4f64(a0, b, acc[0][n], 0, 0, 0);
                acc[1][n] = __builtin_amdgcn_mfma_f64_16x16x4f64(a1, b, acc[1][n], 0, 0, 0);
            }
        }
        __syncthreads();   // vmcnt(0)+barrier: next tile resident, reads done
        cur ^= 1;
    }

    // ---------------- bias (fp64) --------------------------------------------
#pragma unroll
    for (int n = 0; n < 4; ++n) {
        const double bb = (double)bias[wv * 64 + n * 16 + r];
#pragma unroll
        for (int m = 0; m < 2; ++m)
#pragma unroll
            for (int i = 0; i < 4; ++i) acc[m][n][i] += bb;
    }

    // ---------------- per-token L2 norm (cross-wave via 1KB LDS) -------------
    double* partials = (double*)smem_raw;      // [4 waves][32 tok]
    double ss[2][4];
#pragma unroll
    for (int m = 0; m < 2; ++m)
#pragma unroll
        for (int i = 0; i < 4; ++i) {
            double s = 0.0;
#pragma unroll
            for (int n = 0; n < 4; ++n) s = fma(acc[m][n][i], acc[m][n][i], s);
            // sum across the 16 col-lanes sharing this token row
#pragma unroll
            for (int off = 8; off >= 1; off >>= 1) s += __shfl_xor(s, off, 64);
            ss[m][i] = s;
        }
    if (r == 0) {
#pragma unroll
        for (int m = 0; m < 2; ++m)
#pragma unroll
            for (int i = 0; i < 4; ++i)
                partials[wv * 32 + m * 16 + q * 4 + i] = ss[m][i];
    }
    __syncthreads();

    double inv[2][4];
#pragma unroll
    for (int m = 0; m < 2; ++m)
#pragma unroll
        for (int i = 0; i < 4; ++i) {
            const int t = m * 16 + q * 4 + i;
            const double s = partials[t] + partials[32 + t] + partials[64 + t] + partials[96 + t];
            inv[m][i] = 1.0 / fmax(sqrt(s), 1e-12);
        }
    __syncthreads();   // all partials reads done before projn overwrites region

    // write NORMALIZED projn[e][tok] (fp64, exactly 64KB)
    double* projn = (double*)smem_raw;   // [256][32]
#pragma unroll
    for (int m = 0; m < 2; ++m)
#pragma unroll
        for (int n = 0; n < 4; ++n)
#pragma unroll
            for (int i = 0; i < 4; ++i)
                projn[(wv * 64 + n * 16 + r) * 32 + m * 16 + q * 4 + i] = acc[m][n][i] * inv[m][i];
    __syncthreads();

    // ---------------- GEMM2 (f64 MFMA) + fused per-thread top-2 --------------
    double tv1[2][4], tv2[2][4];
    int    ti1[2][4], ti2[2][4];
#pragma unroll
    for (int m = 0; m < 2; ++m)
#pragma unroll
        for (int i = 0; i < 4; ++i) {
            tv1[m][i] = -1e300; tv2[m][i] = -1e300; ti1[m][i] = 0; ti2[m][i] = 0;
        }

    for (int pass = 0; pass < 2; ++pass) {
        const int colbase = wv * 128 + pass * 64;
        d4 acc2[2][4];
#pragma unroll
        for (int m = 0; m < 2; ++m)
#pragma unroll
            for (int n = 0; n < 4; ++n) acc2[m][n] = (d4){0.0, 0.0, 0.0, 0.0};

        const double* cb = cTd + colbase + r;   // B cols from L2-resident cTd
#pragma unroll 4
        for (int kk = 0; kk < 64; ++kk) {
            const int k = kk * 4 + q;
            const double a0 = projn[k * 32 + r];
            const double a1 = projn[k * 32 + 16 + r];
#pragma unroll
            for (int n = 0; n < 4; ++n) {
                const double b = cb[(size_t)k * N_EXP + n * 16];
                acc2[0][n] = __builtin_amdgcn_mfma_f64_16x16x4f64(a0, b, acc2[0][n], 0, 0, 0);
                acc2[1][n] = __builtin_amdgcn_mfma_f64_16x16x4f64(a1, b, acc2[1][n], 0, 0, 0);
            }
        }
#pragma unroll
        for (int m = 0; m < 2; ++m)
#pragma unroll
            for (int i = 0; i < 4; ++i)
#pragma unroll
                for (int n = 0; n < 4; ++n)
                    ins2(acc2[m][n][i], colbase + n * 16 + r,
                         tv1[m][i], ti1[m][i], tv2[m][i], ti2[m][i]);
    }

    // merge top-2 across the 16 col-lanes of each token row
#pragma unroll
    for (int m = 0; m < 2; ++m)
#pragma unroll
        for (int i = 0; i < 4; ++i) {
#pragma unroll
            for (int off = 8; off >= 1; off >>= 1) {
                const double ov1 = __shfl_xor(tv1[m][i], off, 64);
                const int    oi1 = __shfl_xor(ti1[m][i], off, 64);
                const double ov2 = __shfl_xor(tv2[m][i], off, 64);
                const int    oi2 = __shfl_xor(ti2[m][i], off, 64);
                ins2(ov1, oi1, tv1[m][i], ti1[m][i], tv2[m][i], ti2[m][i]);
                ins2(ov2, oi2, tv1[m][i], ti1[m][i], tv2[m][i], ti2[m][i]);
            }
        }

    __syncthreads();                      // projn dead; reuse LDS for candidates
    double* cand = (double*)smem_raw;     // [4 waves][32 tok][4]
    if (r == 0) {
#pragma unroll
        for (int m = 0; m < 2; ++m)
#pragma unroll
            for (int i = 0; i < 4; ++i) {
                const int t = m * 16 + q * 4 + i;
                double* cd = cand + ((wv * 32 + t) << 2);
                cd[0] = tv1[m][i]; cd[1] = (double)ti1[m][i];
                cd[2] = tv2[m][i]; cd[3] = (double)ti2[m][i];
            }
    }
    __syncthreads();

    if (tid < 32) {
        double v1 = -1e300, v2 = -1e300;
        int    i1 = 0, i2 = 0;
        for (int s = 0; s < 4; ++s) {
            const double* cd = cand + ((s * 32 + tid) << 2);
            ins2(cd[0], (int)cd[1], v1, i1, v2, i2);
            ins2(cd[2], (int)cd[3], v1, i1, v2, i2);
        }
        const double e  = exp(v2 - v1);    // <= 1
        const double dn = 1.0 + e;
        const size_t g  = (size_t)tokBase + tid;
        out[g * 2 + 0] = (float)(1.0 / dn);
        out[g * 2 + 1] = (float)(e / dn);
        out[(size_t)2 * N_TOK + g * 2 + 0] = (float)i1;
        out[(size_t)2 * N_TOK + g * 2 + 1] = (float)i2;
    }
}

// ---------------------------------------------------------------------------
extern "C" void kernel_launch(void* const* d_in, const int* in_sizes, int n_in,
                              void* d_out, int out_size, void* d_ws, size_t ws_size,
                              hipStream_t stream)
{
    const float* x       = (const float*)d_in[0];
    const float* W       = (const float*)d_in[1];
    const float* bias    = (const float*)d_in[2];
    const float* centers = (const float*)d_in[3];
    // d_in[4] = top_k (always 2, hard-coded)
    double* cTd = (double*)d_ws;   // 256 x 512 doubles = 1 MB scratch
    float*  out = (float*)d_out;

    center_norm_kernel<<<N_EXP, 64, 0, stream>>>(centers, cTd);
    router_kernel<<<N_TOK / TM, 256, 0, stream>>>(x, W, bias, cTd, out);
}